// Round 1
// baseline (817.151 us; speedup 1.0000x reference)
//
#include <hip/hip_runtime.h>
#include <hip/hip_bf16.h>
#include <stdint.h>

// Problem constants (fixed by the reference setup)
#define NROWS 65536   // B*S = 16*4096
#define DDIM  256
#define KCAND 4096
#define BM    128     // rows per workgroup (phase 1)
#define BN    128     // candidates per tile (phase 1)
#define LDP   264     // padded LDS row (bf16 elems): +8 -> row stride 528B = 132 dwords == 4 mod 32 banks
#define CAP   64      // candidate-list slots per row
#define MARGIN1 1e-3f // phase-1 collection margin (>= 2*2.3e-4 bf16 err + tie window)
#define MARGIN2 1.5e-3f // phase-2 prune margin

typedef __bf16 bf16x8 __attribute__((ext_vector_type(8)));
typedef float  f32x4  __attribute__((ext_vector_type(4)));

__device__ __forceinline__ unsigned short f2bf(float f) {
    // round-to-nearest-even float -> bf16 bits (finite inputs only)
    unsigned u = __float_as_uint(f);
    u += 0x7fffu + ((u >> 16) & 1u);
    return (unsigned short)(u >> 16);
}
__device__ __forceinline__ unsigned fkey(float f) {
    // monotone float -> uint (ascending)
    unsigned u = __float_as_uint(f);
    return (u & 0x80000000u) ? ~u : (u | 0x80000000u);
}
__device__ __forceinline__ float funkey(unsigned k) {
    unsigned u = (k & 0x80000000u) ? (k ^ 0x80000000u) : ~k;
    return __uint_as_float(u);
}

// ---------------------------------------------------------------- phase 0
__global__ void convert_e(const float* __restrict__ e, unsigned short* __restrict__ ebf) {
    int i = blockIdx.x * blockDim.x + threadIdx.x;  // 262144 threads, 4 elems each
    float4 v = ((const float4*)e)[i];
    ushort4 o;
    o.x = f2bf(v.x); o.y = f2bf(v.y); o.z = f2bf(v.z); o.w = f2bf(v.w);
    ((ushort4*)ebf)[i] = o;
}

// ---------------------------------------------------------------- phase 1
// Per WG: 128 rows x all 4096 candidates. x-tile resident bf16 in LDS; loop
// 32 e-tiles. 4 waves in 2x2 layout, each wave 64x64 via 4x4 16x16x32 MFMAs.
// Epilogue: running per-row min (LDS, orderable-uint atomicMin) + collect
// candidates with v <= rowmin + MARGIN1 into global per-row list.
__launch_bounds__(256, 1)
__global__ void phase1(const float* __restrict__ x, const unsigned short* __restrict__ ebf,
                       unsigned* __restrict__ cnt, uint2* __restrict__ list) {
    __shared__ unsigned short lx[BM * LDP];
    __shared__ unsigned short le[BN * LDP];
    __shared__ unsigned rowMinU[BM];

    const int tid = threadIdx.x;
    const int rowBase = blockIdx.x * BM;

    if (tid < BM) rowMinU[tid] = 0xFFFFFFFFu;

    // stage x tile: 128 rows x 256 fp32 -> bf16 (once per WG), coalesced float4
    {
        const float4* xs4 = (const float4*)(x + (size_t)rowBase * DDIM);
        #pragma unroll
        for (int j = 0; j < 32; ++j) {
            int ch = j * 256 + tid;        // 0..8191 chunks of 4 floats
            int r  = ch >> 6, c4 = ch & 63;
            float4 v = xs4[r * 64 + c4];
            ushort4 pk;
            pk.x = f2bf(v.x); pk.y = f2bf(v.y); pk.z = f2bf(v.z); pk.w = f2bf(v.w);
            *(ushort4*)&lx[r * LDP + c4 * 4] = pk;
        }
    }

    const int L  = tid & 63;
    const int w  = tid >> 6;
    const int wr = w >> 1, wc = w & 1;
    const int lq = L >> 4, ln = L & 15;

    for (int ct = 0; ct < 32; ++ct) {
        // stage e tile (bf16, pre-converted): 128x256 -> LDS, 16B chunks
        const uint4* es = (const uint4*)(ebf + (size_t)ct * BN * DDIM);
        #pragma unroll
        for (int j = 0; j < 16; ++j) {
            int ch = j * 256 + tid;        // 0..4095 chunks of 8 bf16
            int r  = ch >> 5, c8 = ch & 31;
            *(uint4*)&le[r * LDP + c8 * 8] = es[r * 32 + c8];
        }
        __syncthreads();

        f32x4 acc[4][4];
        #pragma unroll
        for (int a = 0; a < 4; ++a)
            #pragma unroll
            for (int b = 0; b < 4; ++b)
                acc[a][b] = (f32x4){0.f, 0.f, 0.f, 0.f};

        #pragma unroll
        for (int ks = 0; ks < 8; ++ks) {
            bf16x8 fa[4], fb[4];
            #pragma unroll
            for (int t = 0; t < 4; ++t)
                fa[t] = *(const bf16x8*)&lx[(wr * 64 + t * 16 + ln) * LDP + ks * 32 + lq * 8];
            #pragma unroll
            for (int t = 0; t < 4; ++t)
                fb[t] = *(const bf16x8*)&le[(wc * 64 + t * 16 + ln) * LDP + ks * 32 + lq * 8];
            #pragma unroll
            for (int a = 0; a < 4; ++a)
                #pragma unroll
                for (int b = 0; b < 4; ++b)
                    acc[a][b] = __builtin_amdgcn_mfma_f32_16x16x32_bf16(fa[a], fb[b], acc[a][b], 0, 0, 0);
        }

        // merge running per-row min (v = -2*C; A and B_k irrelevant for selection)
        #pragma unroll
        for (int a = 0; a < 4; ++a) {
            #pragma unroll
            for (int r = 0; r < 4; ++r) {
                float m = -2.f * acc[a][0][r];
                m = fminf(m, -2.f * acc[a][1][r]);
                m = fminf(m, -2.f * acc[a][2][r]);
                m = fminf(m, -2.f * acc[a][3][r]);
                int lrow = wr * 64 + a * 16 + lq * 4 + r;
                atomicMin(&rowMinU[lrow], fkey(m));
            }
        }
        __syncthreads();

        // collect candidates within margin of current running min
        #pragma unroll
        for (int a = 0; a < 4; ++a) {
            #pragma unroll
            for (int r = 0; r < 4; ++r) {
                int lrow = wr * 64 + a * 16 + lq * 4 + r;
                float thr = funkey(rowMinU[lrow]) + MARGIN1;
                #pragma unroll
                for (int b = 0; b < 4; ++b) {
                    float v = -2.f * acc[a][b][r];
                    if (v <= thr) {
                        int grow = rowBase + lrow;
                        unsigned k = (unsigned)(ct * BN + wc * 64 + b * 16 + ln);
                        unsigned idx = atomicAdd(&cnt[grow], 1u);
                        if (idx < CAP) {
                            uint2 ent; ent.x = __float_as_uint(v); ent.y = k;
                            list[(size_t)grow * CAP + idx] = ent;
                        }
                    }
                }
            }
        }
        __syncthreads();  // collect done before next iteration overwrites le / re-mins
    }
}

// ---------------------------------------------------------------- phase 2
// Per row (1 wave): exact fp32 rescue of collected candidates, np-semantics:
// r = fl(fl(A + b_k) - C2_k), C2_k = sequential FMA over d of (2*x_d)*e_d,
// argmin with lowest-index tie-break; then gather + write.
__device__ __forceinline__ float exact_r(const float* __restrict__ xs, float A,
                                         const float* __restrict__ er) {
    float b = 0.f, acc = 0.f;
    #pragma unroll 8
    for (int d = 0; d < DDIM; ++d) {
        float e = er[d];
        b   = fmaf(e, e, b);                 // b_k (rounds away vs A anyway)
        acc = fmaf(2.0f * xs[d], e, acc);    // (2x) @ e^T, sequential ascending d
    }
    return (A + b) - acc;
}

__launch_bounds__(64)
__global__ void phase2(const float* __restrict__ x, const float* __restrict__ emb,
                       const unsigned* __restrict__ cnt, const uint2* __restrict__ list,
                       float* __restrict__ outq, float* __restrict__ outp) {
    __shared__ float xs[DDIM];
    const int row = blockIdx.x;
    const int L   = threadIdx.x;

    float4 v = ((const float4*)(x + (size_t)row * DDIM))[L];
    *(float4*)&xs[L * 4] = v;
    // A = sum(x^2): fp64 reduce then round -> within ~1 ulp of np's pairwise fp32
    // (quantized ordering invariant under integer-ulp shifts of A)
    double s = (double)v.x * v.x + (double)v.y * v.y + (double)v.z * v.z + (double)v.w * v.w;
    #pragma unroll
    for (int o = 32; o; o >>= 1) s += __shfl_xor(s, o, 64);
    float A = (float)s;
    __syncthreads();

    unsigned n = cnt[row];
    unsigned long long key = 0xFFFFFFFFFFFFFFFFull;

    if (n > 0 && n <= CAP) {
        float vv = INFINITY; unsigned kk = 0u;
        if (L < (int)n) {
            uint2 e = list[(size_t)row * CAP + L];
            vv = __uint_as_float(e.x); kk = e.y;
        }
        float mv = vv;
        #pragma unroll
        for (int o = 32; o; o >>= 1) mv = fminf(mv, __shfl_xor(mv, o, 64));
        if (L < (int)n && vv <= mv + MARGIN2) {
            float r = exact_r(xs, A, emb + (size_t)kk * DDIM);
            key = ((unsigned long long)fkey(r) << 32) | (unsigned long long)kk;
        }
    } else {
        // overflow / empty fallback: full exact scan (near-impossible path)
        for (int base = 0; base < KCAND; base += 64) {
            unsigned k = (unsigned)(base + L);
            float r = exact_r(xs, A, emb + (size_t)k * DDIM);
            unsigned long long cand = ((unsigned long long)fkey(r) << 32) | (unsigned long long)k;
            key = (cand < key) ? cand : key;
        }
    }
    #pragma unroll
    for (int o = 32; o; o >>= 1) {
        unsigned long long other = __shfl_xor(key, o, 64);
        key = (other < key) ? other : key;
    }
    unsigned kstar = (unsigned)(key & 0xFFFFFFFFull);

    // outputs: quantized gather (fp32) + proposal as float
    float4 q = ((const float4*)(emb + (size_t)kstar * DDIM))[L];
    ((float4*)(outq + (size_t)row * DDIM))[L] = q;
    if (L == 0) outp[row] = (float)kstar;
}

// ---------------------------------------------------------------- launch
extern "C" void kernel_launch(void* const* d_in, const int* in_sizes, int n_in,
                              void* d_out, int out_size, void* d_ws, size_t ws_size,
                              hipStream_t stream) {
    const float* x   = (const float*)d_in[0];   // [65536, 256] fp32
    const float* emb = (const float*)d_in[1];   // [4096, 256] fp32
    float* outq = (float*)d_out;                       // [65536,256]
    float* outp = outq + (size_t)NROWS * DDIM;         // [65536] (indices as float)

    char* ws = (char*)d_ws;
    unsigned short* ebf = (unsigned short*)ws;                              // 2 MiB
    unsigned* cnt = (unsigned*)(ws + (size_t)2 * 1024 * 1024);              // 256 KiB
    uint2* list   = (uint2*)(ws + (size_t)2 * 1024 * 1024 + 256 * 1024);    // 32 MiB

    hipMemsetAsync(cnt, 0, (size_t)NROWS * sizeof(unsigned), stream);
    convert_e<<<1024, 256, 0, stream>>>(emb, ebf);
    phase1<<<NROWS / BM, 256, 0, stream>>>(x, ebf, cnt, list);
    phase2<<<NROWS, 64, 0, stream>>>(x, emb, cnt, list, outq, outp);
}